// Round 6
// baseline (543.369 us; speedup 1.0000x reference)
//
#include <hip/hip_runtime.h>
#include <math.h>

#define N_NODES 100000
#define N_EDGES 1250000
#define IN_DIM 12
#define HID 64
#define N_LAYERS 3
#define LN_EPS 1e-5f
#define SLOPE 0.01f

#define NODE_BLOCKS ((N_NODES + 3) / 4)     // 4 waves (nodes) per 256-thread block
#define EDGE_TBLOCKS ((N_EDGES + 255) / 256)
#define SCAN_BLOCKS ((N_NODES + 1023) / 1024)   // 98
#define MFMA_BLOCKS ((N_NODES + 63) / 64)       // 64 nodes per 256-thread block
#define EDGE_CHUNK 2048
#define EDGE_BLOCKS ((N_EDGES + EDGE_CHUNK - 1) / EDGE_CHUNK)   // 611

#define LEW_SCALE 2048.0f
#define LEW_INV (1.0f / 2048.0f)

typedef short bf16x8 __attribute__((ext_vector_type(8)));
typedef float f32x4 __attribute__((ext_vector_type(4)));

static __device__ __forceinline__ unsigned short f2bf(float f) {
  union { float f; unsigned int u; } v; v.f = f;
  unsigned int r = v.u + 0x7FFFu + ((v.u >> 16) & 1u);   // RNE
  return (unsigned short)(r >> 16);
}
static __device__ __forceinline__ float bf2f(unsigned short u) {
  union { unsigned int u; float f; } v; v.u = ((unsigned int)u) << 16;
  return v.f;
}

// ---------------- input projection: h = x @ in_W + in_b ----------------
__global__ void k_in_proj(const float* __restrict__ x,
                          const float* __restrict__ W,   // [12][64]
                          const float* __restrict__ b,
                          float* __restrict__ h) {
  __shared__ float sW[IN_DIM * HID];
  for (int i = threadIdx.x; i < IN_DIM * HID; i += blockDim.x) sW[i] = W[i];
  __syncthreads();
  int wave = threadIdx.x >> 6, lane = threadIdx.x & 63;
  int n = blockIdx.x * 4 + wave;
  if (n >= N_NODES) return;
  float acc = b[lane];
#pragma unroll
  for (int k = 0; k < IN_DIM; ++k)
    acc += x[n * IN_DIM + k] * sW[k * HID + lane];
  h[n * HID + lane] = acc;
}

// ---------------- CSR build (once per launch) ----------------
__global__ void k_hist(const int* __restrict__ ei, int* __restrict__ deg) {
  int e = blockIdx.x * 256 + threadIdx.x;
  if (e >= N_EDGES) return;
  atomicAdd(&deg[ei[e]], 1);
}

__global__ void k_blocksums(const int* __restrict__ deg, int* __restrict__ bsum) {
  __shared__ int sm[1024];
  int i = blockIdx.x * 1024 + threadIdx.x;
  sm[threadIdx.x] = (i < N_NODES) ? deg[i] : 0;
  __syncthreads();
  for (int st = 512; st > 0; st >>= 1) {
    if (threadIdx.x < st) sm[threadIdx.x] += sm[threadIdx.x + st];
    __syncthreads();
  }
  if (threadIdx.x == 0) bsum[blockIdx.x] = sm[0];
}

__global__ void k_scan_bsums(int* __restrict__ bsum, int nb) {  // single block, 128 thr
  __shared__ int sm[128];
  int v = (threadIdx.x < nb) ? bsum[threadIdx.x] : 0;
  sm[threadIdx.x] = v;
  __syncthreads();
  for (int st = 1; st < 128; st <<= 1) {
    int t = (threadIdx.x >= st) ? sm[threadIdx.x - st] : 0;
    __syncthreads();
    sm[threadIdx.x] += t;
    __syncthreads();
  }
  if (threadIdx.x < nb) bsum[threadIdx.x] = sm[threadIdx.x] - v;  // exclusive
}

__global__ void k_scan_final(const int* __restrict__ deg, const int* __restrict__ bsum,
                             int* __restrict__ rowptr, int* __restrict__ cursor) {
  __shared__ int sm[1024];
  int i = blockIdx.x * 1024 + threadIdx.x;
  int v = (i < N_NODES) ? deg[i] : 0;
  sm[threadIdx.x] = v;
  __syncthreads();
  for (int st = 1; st < 1024; st <<= 1) {
    int t = (threadIdx.x >= st) ? sm[threadIdx.x - st] : 0;
    __syncthreads();
    sm[threadIdx.x] += t;
    __syncthreads();
  }
  int excl = sm[threadIdx.x] - v + bsum[blockIdx.x];
  if (i < N_NODES) { rowptr[i] = excl; cursor[i] = excl; }
}

// scatter one PACKED 4B record per edge: (col << 15) | q15(-log(ew))
__global__ void k_fill(const int* __restrict__ ei, const float* __restrict__ ew,
                       int* __restrict__ cursor, unsigned* __restrict__ packed) {
  int e = blockIdx.x * 256 + threadIdx.x;
  if (e >= N_EDGES) return;
  int r = ei[e], c = ei[N_EDGES + e];
  float lew = __logf(ew[e]);
  lew = fmaxf(lew, -15.9995f);
  unsigned q = (unsigned)(-lew * LEW_SCALE + 0.5f);
  if (q > 32767u) q = 32767u;
  int p = atomicAdd(&cursor[r], 1);
  packed[p] = ((unsigned)c << 15) | q;
}

// ---------------- per-layer u = W @ a  (alpha decomposition) ----------------
__global__ void k_prep(const float* __restrict__ lin_W,  // [3][64][64]
                       const float* __restrict__ lin_b,  // [3][64]
                       const float* __restrict__ att_W,  // [3][128]
                       float* __restrict__ uvec,         // [3][2][64]
                       float* __restrict__ ucst) {       // [3][2]
  int l = blockIdx.x, j = threadIdx.x;
  const float* Wl = lin_W + l * HID * HID;
  const float* a1 = att_W + l * 2 * HID;
  const float* a2 = a1 + HID;
  float s1 = 0.f, s2 = 0.f;
  for (int c = 0; c < HID; ++c) {
    float w = Wl[j * HID + c];
    s1 += w * a1[c];
    s2 += w * a2[c];
  }
  uvec[l * 128 + j] = s1;
  uvec[l * 128 + 64 + j] = s2;
  float t1 = lin_b[l * HID + j] * a1[j];
  float t2 = lin_b[l * HID + j] * a2[j];
#pragma unroll
  for (int off = 32; off > 0; off >>= 1) {
    t1 += __shfl_xor(t1, off, 64);
    t2 += __shfl_xor(t2, off, 64);
  }
  if (j == 0) { ucst[l * 2] = t1; ucst[l * 2 + 1] = t2; }
}

// ---------------- MFMA linear: hl = h@W + b (fp32 + bf16 mirror); alphas ----------------
__global__ void k_lin_mfma(const float* __restrict__ h,
                           const float* __restrict__ W,     // [64][64] this layer
                           const float* __restrict__ bias,  // [64]
                           const float* __restrict__ uvec,  // [2][64] this layer
                           const float* __restrict__ ucst,  // [2]
                           float* __restrict__ hl,
                           unsigned short* __restrict__ hl2, // bf16 mirror
                           float* __restrict__ alpha1,
                           float* __restrict__ alpha2) {
  __shared__ unsigned short Wt[HID * 72];  // Wt[n][k] bf16, row stride 72
  for (int idx = threadIdx.x; idx < HID * HID; idx += 256) {
    int k = idx >> 6, n = idx & 63;
    Wt[n * 72 + k] = f2bf(W[idx]);
  }
  __syncthreads();

  int wave = threadIdx.x >> 6, lane = threadIdx.x & 63;
  int g = lane >> 4, r = lane & 15;
  int nb = blockIdx.x * 64 + wave * 16;
  int row = nb + r;
  bool rowok = row < N_NODES;

  f32x4 f0 = {0,0,0,0}, f1 = {0,0,0,0}, f2v = {0,0,0,0}, f3 = {0,0,0,0};
  if (rowok) {
    const float* hrow = h + (size_t)row * HID;
    f0  = *(const f32x4*)(hrow + g * 8);
    f1  = *(const f32x4*)(hrow + g * 8 + 4);
    f2v = *(const f32x4*)(hrow + 32 + g * 8);
    f3  = *(const f32x4*)(hrow + 32 + g * 8 + 4);
  }
  bf16x8 a0, a1f;
#pragma unroll
  for (int i = 0; i < 4; ++i) {
    a0[i]      = (short)f2bf(f0[i]);
    a0[i + 4]  = (short)f2bf(f1[i]);
    a1f[i]     = (short)f2bf(f2v[i]);
    a1f[i + 4] = (short)f2bf(f3[i]);
  }

  f32x4 acc[4] = {{0,0,0,0},{0,0,0,0},{0,0,0,0},{0,0,0,0}};
#pragma unroll
  for (int nt = 0; nt < 4; ++nt) {
    bf16x8 b0 = *(const bf16x8*)&Wt[(nt * 16 + r) * 72 + g * 8];
    bf16x8 b1 = *(const bf16x8*)&Wt[(nt * 16 + r) * 72 + 32 + g * 8];
    acc[nt] = __builtin_amdgcn_mfma_f32_16x16x32_bf16(a0, b0, acc[nt], 0, 0, 0);
    acc[nt] = __builtin_amdgcn_mfma_f32_16x16x32_bf16(a1f, b1, acc[nt], 0, 0, 0);
  }

  // alphas from fp32 h fragments
  {
    const float* u1 = uvec;
    const float* u2 = uvec + HID;
    f32x4 ua = *(const f32x4*)(u1 + g * 8),      ub = *(const f32x4*)(u1 + g * 8 + 4);
    f32x4 uc = *(const f32x4*)(u1 + 32 + g * 8), ud = *(const f32x4*)(u1 + 32 + g * 8 + 4);
    float p1 = f0[0]*ua[0]+f0[1]*ua[1]+f0[2]*ua[2]+f0[3]*ua[3]
             + f1[0]*ub[0]+f1[1]*ub[1]+f1[2]*ub[2]+f1[3]*ub[3]
             + f2v[0]*uc[0]+f2v[1]*uc[1]+f2v[2]*uc[2]+f2v[3]*uc[3]
             + f3[0]*ud[0]+f3[1]*ud[1]+f3[2]*ud[2]+f3[3]*ud[3];
    ua = *(const f32x4*)(u2 + g * 8);      ub = *(const f32x4*)(u2 + g * 8 + 4);
    uc = *(const f32x4*)(u2 + 32 + g * 8); ud = *(const f32x4*)(u2 + 32 + g * 8 + 4);
    float p2 = f0[0]*ua[0]+f0[1]*ua[1]+f0[2]*ua[2]+f0[3]*ua[3]
             + f1[0]*ub[0]+f1[1]*ub[1]+f1[2]*ub[2]+f1[3]*ub[3]
             + f2v[0]*uc[0]+f2v[1]*uc[1]+f2v[2]*uc[2]+f2v[3]*uc[3]
             + f3[0]*ud[0]+f3[1]*ud[1]+f3[2]*ud[2]+f3[3]*ud[3];
    p1 += __shfl_xor(p1, 16, 64); p1 += __shfl_xor(p1, 32, 64);
    p2 += __shfl_xor(p2, 16, 64); p2 += __shfl_xor(p2, 32, 64);
    if (g == 0 && rowok) {
      alpha1[row] = p1 + ucst[0];
      alpha2[row] = p2 + ucst[1];
    }
  }

  // store hl (+bias) fp32 + bf16 mirror. D: col = nt*16 + r, node = nb + g*4 + reg
#pragma unroll
  for (int nt = 0; nt < 4; ++nt) {
    float bv = bias[nt * 16 + r];
#pragma unroll
    for (int reg = 0; reg < 4; ++reg) {
      int n2 = nb + g * 4 + reg;
      if (n2 < N_NODES) {
        float v = acc[nt][reg] + bv;
        hl[(size_t)n2 * HID + nt * 16 + r] = v;
        hl2[(size_t)n2 * HID + nt * 16 + r] = f2bf(v);
      }
    }
  }
}

// ---------------- per-layer edge pass (ORIGINAL order) + fused final combine ----------------
__global__ void k_edge(const int* __restrict__ ei,
                       const float* __restrict__ alpha1,
                       const float* __restrict__ alpha2,
                       const float* __restrict__ attB,
                       float* __restrict__ pmax,
                       float* __restrict__ psum,
                       int* __restrict__ counter,
                       float* __restrict__ red) {
  int t = threadIdx.x;
  int base = blockIdx.x * EDGE_CHUNK;
  float ab = attB[0];
  float m = -INFINITY, sum = 0.f;
#pragma unroll
  for (int i = 0; i < 8; ++i) {
    int e = base + i * 256 + t;
    if (e < N_EDGES) {
      int r = ei[e], c = ei[N_EDGES + e];
      float sc = alpha1[r] + alpha2[c] + ab;
      sc = sc > 0.f ? sc : SLOPE * sc;
      if (sc > m) { sum *= __expf(m - sc); m = sc; }
      sum += __expf(sc - m);
    }
  }
  __shared__ float smax[256], ssum[256];
  __shared__ bool last;
  smax[t] = m; ssum[t] = sum;
  __syncthreads();
  for (int st = 128; st > 0; st >>= 1) {
    if (t < st) {
      float ma = smax[t], mb = smax[t + st];
      float sa = ssum[t], sb = ssum[t + st];
      float mm = fmaxf(ma, mb);
      float ss = 0.f;
      if (mm != -INFINITY)
        ss = (ma == -INFINITY ? 0.f : sa * __expf(ma - mm))
           + (mb == -INFINITY ? 0.f : sb * __expf(mb - mm));
      smax[t] = mm; ssum[t] = ss;
    }
    __syncthreads();
  }
  if (t == 0) {
    pmax[blockIdx.x] = smax[0];
    psum[blockIdx.x] = ssum[0];
    __threadfence();
    int old = atomicAdd(counter, 1);
    last = (old == (int)gridDim.x - 1);
  }
  __syncthreads();
  if (!last) return;
  // final combine in the last-arriving block
  __threadfence();
  volatile const float* vpm = pmax;
  volatile const float* vps = psum;
  float m2 = -INFINITY, s2 = 0.f;
  for (int i = t; i < (int)gridDim.x; i += 256) {
    float mb = vpm[i], sb = vps[i];
    if (mb != -INFINITY) {
      if (mb > m2) { s2 *= __expf(m2 - mb); m2 = mb; }
      s2 += sb * __expf(mb - m2);
    }
  }
  __syncthreads();   // reuse of smax/ssum
  smax[t] = m2; ssum[t] = s2;
  __syncthreads();
  for (int st = 128; st > 0; st >>= 1) {
    if (t < st) {
      float ma = smax[t], mb = smax[t + st];
      float sa = ssum[t], sb = ssum[t + st];
      float mm = fmaxf(ma, mb);
      float ss = 0.f;
      if (mm != -INFINITY)
        ss = (ma == -INFINITY ? 0.f : sa * __expf(ma - mm))
           + (mb == -INFINITY ? 0.f : sb * __expf(mb - mm));
      smax[t] = mm; ssum[t] = ss;
    }
    __syncthreads();
  }
  if (t == 0) {
    red[0] = smax[0];
    red[1] = ssum[0];
    *counter = 0;   // self-reset for next layer / next replay
  }
}

// ---------------- fused CSR aggregate (bf16 gather, score recompute) + relu + LN + residual ----------------
__global__ void k_agg_update(const int* __restrict__ rowptr,
                             const int* __restrict__ deg,
                             const unsigned* __restrict__ packed,
                             const float* __restrict__ alpha1,
                             const float* __restrict__ alpha2,
                             const float* __restrict__ attB,
                             const float* __restrict__ red,  // [0]=M, [1]=S
                             const float* __restrict__ hl,
                             const unsigned short* __restrict__ hl2,
                             const float* __restrict__ g,
                             const float* __restrict__ b,
                             float* __restrict__ h) {
  int wave = threadIdx.x >> 6, lane = threadIdx.x & 63;
  int n = blockIdx.x * 4 + wave;
  if (n >= N_NODES) return;
  float M = red[0];
  float a1n = alpha1[n] + attB[0] - M;   // fold constants: sc-M = leaky(a1n0+alpha2+ab)-M
  float a1n0 = alpha1[n] + attB[0];
  int beg = rowptr[n];
  int end = beg + deg[n];
  float acc = 0.f;
  int k = beg;
  (void)a1n;
  for (; k + 3 < end; k += 4) {
    unsigned w0 = packed[k],     w1 = packed[k + 1];
    unsigned w2 = packed[k + 2], w3 = packed[k + 3];
    unsigned c0 = w0 >> 15, c1 = w1 >> 15, c2 = w2 >> 15, c3 = w3 >> 15;
    float sc0 = a1n0 + alpha2[c0]; sc0 = sc0 > 0.f ? sc0 : SLOPE * sc0;
    float sc1 = a1n0 + alpha2[c1]; sc1 = sc1 > 0.f ? sc1 : SLOPE * sc1;
    float sc2 = a1n0 + alpha2[c2]; sc2 = sc2 > 0.f ? sc2 : SLOPE * sc2;
    float sc3 = a1n0 + alpha2[c3]; sc3 = sc3 > 0.f ? sc3 : SLOPE * sc3;
    float e0 = __expf(sc0 - M - (float)(w0 & 0x7FFFu) * LEW_INV);
    float e1 = __expf(sc1 - M - (float)(w1 & 0x7FFFu) * LEW_INV);
    float e2 = __expf(sc2 - M - (float)(w2 & 0x7FFFu) * LEW_INV);
    float e3 = __expf(sc3 - M - (float)(w3 & 0x7FFFu) * LEW_INV);
    float v0 = bf2f(hl2[(size_t)c0 * HID + lane]);
    float v1 = bf2f(hl2[(size_t)c1 * HID + lane]);
    float v2 = bf2f(hl2[(size_t)c2 * HID + lane]);
    float v3 = bf2f(hl2[(size_t)c3 * HID + lane]);
    acc += e0 * v0 + e1 * v1 + e2 * v2 + e3 * v3;
  }
  for (; k < end; ++k) {
    unsigned w0 = packed[k];
    unsigned c0 = w0 >> 15;
    float sc0 = a1n0 + alpha2[c0]; sc0 = sc0 > 0.f ? sc0 : SLOPE * sc0;
    acc += __expf(sc0 - M - (float)(w0 & 0x7FFFu) * LEW_INV) * bf2f(hl2[(size_t)c0 * HID + lane]);
  }

  float inv = 1.0f / red[1];
  float v = hl[(size_t)n * HID + lane] + acc * inv;
  v = fmaxf(v, 0.f);
  float m = v;
#pragma unroll
  for (int off = 32; off > 0; off >>= 1) m += __shfl_xor(m, off, 64);
  m *= (1.0f / HID);
  float d = v - m;
  float var = d * d;
#pragma unroll
  for (int off = 32; off > 0; off >>= 1) var += __shfl_xor(var, off, 64);
  var *= (1.0f / HID);
  float nv = d * rsqrtf(var + LN_EPS);
  h[(size_t)n * HID + lane] += nv * g[lane] + b[lane];
}

// ---------------- output head via MFMA ----------------
__global__ void k_out_mfma(const float* __restrict__ h,
                           const float* __restrict__ W1,  // [64][32]
                           const float* __restrict__ b1,  // [32]
                           const float* __restrict__ W2,  // [32]
                           const float* __restrict__ b2,  // [1]
                           float* __restrict__ out) {
  __shared__ unsigned short W1t[32 * 72];  // W1t[m][k] bf16
  __shared__ float sW2[32];
  for (int idx = threadIdx.x; idx < HID * 32; idx += 256) {
    int k = idx >> 5, m = idx & 31;
    W1t[m * 72 + k] = f2bf(W1[idx]);
  }
  if (threadIdx.x < 32) sW2[threadIdx.x] = W2[threadIdx.x];
  __syncthreads();

  int wave = threadIdx.x >> 6, lane = threadIdx.x & 63;
  int g = lane >> 4, r = lane & 15;
  int nb = blockIdx.x * 64 + wave * 16;
  int row = nb + r;
  bool rowok = row < N_NODES;

  f32x4 f0 = {0,0,0,0}, f1 = {0,0,0,0}, f2v = {0,0,0,0}, f3 = {0,0,0,0};
  if (rowok) {
    const float* hrow = h + (size_t)row * HID;
    f0  = *(const f32x4*)(hrow + g * 8);
    f1  = *(const f32x4*)(hrow + g * 8 + 4);
    f2v = *(const f32x4*)(hrow + 32 + g * 8);
    f3  = *(const f32x4*)(hrow + 32 + g * 8 + 4);
  }
  bf16x8 a0, a1f;
#pragma unroll
  for (int i = 0; i < 4; ++i) {
    a0[i]      = (short)f2bf(f0[i]);
    a0[i + 4]  = (short)f2bf(f1[i]);
    a1f[i]     = (short)f2bf(f2v[i]);
    a1f[i + 4] = (short)f2bf(f3[i]);
  }

  f32x4 acc[2] = {{0,0,0,0},{0,0,0,0}};
#pragma unroll
  for (int mt = 0; mt < 2; ++mt) {
    bf16x8 b0 = *(const bf16x8*)&W1t[(mt * 16 + r) * 72 + g * 8];
    bf16x8 b1v = *(const bf16x8*)&W1t[(mt * 16 + r) * 72 + 32 + g * 8];
    acc[mt] = __builtin_amdgcn_mfma_f32_16x16x32_bf16(a0, b0, acc[mt], 0, 0, 0);
    acc[mt] = __builtin_amdgcn_mfma_f32_16x16x32_bf16(a1f, b1v, acc[mt], 0, 0, 0);
  }

  float part[4];
#pragma unroll
  for (int reg = 0; reg < 4; ++reg) {
    float p = 0.f;
#pragma unroll
    for (int mt = 0; mt < 2; ++mt) {
      float z = acc[mt][reg] + b1[mt * 16 + r];
      p += fmaxf(z, 0.f) * sW2[mt * 16 + r];
    }
    p += __shfl_xor(p, 1, 64);
    p += __shfl_xor(p, 2, 64);
    p += __shfl_xor(p, 4, 64);
    p += __shfl_xor(p, 8, 64);
    part[reg] = p;
  }
  if (r == 0) {
    float bb = b2[0];
#pragma unroll
    for (int reg = 0; reg < 4; ++reg) {
      int n2 = nb + g * 4 + reg;
      if (n2 < N_NODES)
        out[n2] = 1.0f / (1.0f + expf(-(part[reg] + bb)));
    }
  }
}

extern "C" void kernel_launch(void* const* d_in, const int* in_sizes, int n_in,
                              void* d_out, int out_size, void* d_ws, size_t ws_size,
                              hipStream_t stream) {
  const float* x      = (const float*)d_in[0];
  const int*   ei     = (const int*)d_in[1];     // [2][E]
  const float* ew     = (const float*)d_in[2];
  const float* in_W   = (const float*)d_in[3];
  const float* in_b   = (const float*)d_in[4];
  const float* lin_W  = (const float*)d_in[5];   // [3][64][64]
  const float* lin_b  = (const float*)d_in[6];   // [3][64]
  const float* att_W  = (const float*)d_in[7];   // [3][128]
  const float* att_b  = (const float*)d_in[8];   // [3]
  const float* ln_g   = (const float*)d_in[9];   // [3][64]
  const float* ln_b   = (const float*)d_in[10];  // [3][64]
  const float* out1_W = (const float*)d_in[11];  // [64][32]
  const float* out1_b = (const float*)d_in[12];  // [32]
  const float* out2_W = (const float*)d_in[13];  // [32]
  const float* out2_b = (const float*)d_in[14];  // [1]
  float* out = (float*)d_out;

  float* ws = (float*)d_ws;
  float* h            = ws;                         // 6.4M f
  float* hl           = ws + 6400000;               // 6.4M f
  unsigned short* hl2 = (unsigned short*)(ws + 12800000);  // 6.4M bf16 (3.2M f)
  unsigned* packed    = (unsigned*)(ws + 16000000); // 1.25M u32
  int* deg            = (int*)(ws + 17300000);      // 100000 ints (+1 counter)
  int* counter        = deg + N_NODES;              // ticket counter (memset with deg)
  int* rowptr         = (int*)(ws + 17401000);
  int* cursor         = (int*)(ws + 17502000);
  float* alpha1       = ws + 17603000;
  float* alpha2       = ws + 17704000;
  float* pmax         = ws + 17805000;              // 1024
  float* psum         = ws + 17806024;              // 1024
  float* red          = ws + 17807048;              // [0]=M, [1]=S
  float* uvec         = ws + 17807050;              // [3][2][64]
  float* ucst         = ws + 17807434;              // [3][2]
  int* bsum           = (int*)(ws + 17807442);      // 128

  // ---- one-time CSR build ----
  hipMemsetAsync(deg, 0, (N_NODES + 1) * sizeof(int), stream);  // deg + ticket counter
  k_hist<<<EDGE_TBLOCKS, 256, 0, stream>>>(ei, deg);
  k_blocksums<<<SCAN_BLOCKS, 1024, 0, stream>>>(deg, bsum);
  k_scan_bsums<<<1, 128, 0, stream>>>(bsum, SCAN_BLOCKS);
  k_scan_final<<<SCAN_BLOCKS, 1024, 0, stream>>>(deg, bsum, rowptr, cursor);
  k_fill<<<EDGE_TBLOCKS, 256, 0, stream>>>(ei, ew, cursor, packed);

  k_prep<<<N_LAYERS, 64, 0, stream>>>(lin_W, lin_b, att_W, uvec, ucst);
  k_in_proj<<<NODE_BLOCKS, 256, 0, stream>>>(x, in_W, in_b, h);

  for (int i = 0; i < N_LAYERS; ++i) {
    k_lin_mfma<<<MFMA_BLOCKS, 256, 0, stream>>>(h, lin_W + i * HID * HID, lin_b + i * HID,
                                                uvec + i * 128, ucst + i * 2,
                                                hl, hl2, alpha1, alpha2);
    k_edge<<<EDGE_BLOCKS, 256, 0, stream>>>(ei, alpha1, alpha2, att_b + i,
                                            pmax, psum, counter, red);
    k_agg_update<<<NODE_BLOCKS, 256, 0, stream>>>(rowptr, deg, packed, alpha1, alpha2,
                                                  att_b + i, red,
                                                  hl, hl2, ln_g + i * HID, ln_b + i * HID, h);
  }

  k_out_mfma<<<MFMA_BLOCKS, 256, 0, stream>>>(h, out1_W, out1_b, out2_W, out2_b, out);
}

// Round 7
// 479.635 us; speedup vs baseline: 1.1329x; 1.1329x over previous
//
#include <hip/hip_runtime.h>
#include <math.h>

#define N_NODES 100000
#define N_EDGES 1250000
#define IN_DIM 12
#define HID 64
#define N_LAYERS 3
#define LN_EPS 1e-5f
#define SLOPE 0.01f

#define NODE_BLOCKS ((N_NODES + 3) / 4)     // 4 waves (nodes) per 256-thread block
#define EDGE_TBLOCKS ((N_EDGES + 255) / 256)
#define SCAN_BLOCKS ((N_NODES + 1023) / 1024)   // 98
#define MFMA_BLOCKS ((N_NODES + 63) / 64)       // 64 nodes per 256-thread block
#define EDGE_CHUNK 2048
#define EDGE_BLOCKS ((N_EDGES + EDGE_CHUNK - 1) / EDGE_CHUNK)   // 611

#define BUCKETS 256
#define BUCKET_NODES 391                         // 256*391 = 100096 >= N_NODES
#define P1_EDGES 4096
#define P1_BLOCKS ((N_EDGES + P1_EDGES - 1) / P1_EDGES)  // 306

#define LEW_SCALE 2048.0f
#define LEW_INV (1.0f / 2048.0f)

typedef short bf16x8 __attribute__((ext_vector_type(8)));
typedef float f32x4 __attribute__((ext_vector_type(4)));

static __device__ __forceinline__ unsigned short f2bf(float f) {
  union { float f; unsigned int u; } v; v.f = f;
  unsigned int r = v.u + 0x7FFFu + ((v.u >> 16) & 1u);   // RNE
  return (unsigned short)(r >> 16);
}
static __device__ __forceinline__ float bf2f(unsigned short u) {
  union { unsigned int u; float f; } v; v.u = ((unsigned int)u) << 16;
  return v.f;
}

// ---------------- input projection: h = x @ in_W + in_b ----------------
__global__ void k_in_proj(const float* __restrict__ x,
                          const float* __restrict__ W,   // [12][64]
                          const float* __restrict__ b,
                          float* __restrict__ h) {
  __shared__ float sW[IN_DIM * HID];
  for (int i = threadIdx.x; i < IN_DIM * HID; i += blockDim.x) sW[i] = W[i];
  __syncthreads();
  int wave = threadIdx.x >> 6, lane = threadIdx.x & 63;
  int n = blockIdx.x * 4 + wave;
  if (n >= N_NODES) return;
  float acc = b[lane];
#pragma unroll
  for (int k = 0; k < IN_DIM; ++k)
    acc += x[n * IN_DIM + k] * sW[k * HID + lane];
  h[n * HID + lane] = acc;
}

// ---------------- CSR build (once per launch) ----------------
__global__ void k_hist(const int* __restrict__ ei, int* __restrict__ deg) {
  int e = blockIdx.x * 256 + threadIdx.x;
  if (e >= N_EDGES) return;
  atomicAdd(&deg[ei[e]], 1);
}

__global__ void k_blocksums(const int* __restrict__ deg, int* __restrict__ bsum) {
  __shared__ int sm[1024];
  int i = blockIdx.x * 1024 + threadIdx.x;
  sm[threadIdx.x] = (i < N_NODES) ? deg[i] : 0;
  __syncthreads();
  for (int st = 512; st > 0; st >>= 1) {
    if (threadIdx.x < st) sm[threadIdx.x] += sm[threadIdx.x + st];
    __syncthreads();
  }
  if (threadIdx.x == 0) bsum[blockIdx.x] = sm[0];
}

__global__ void k_scan_bsums(int* __restrict__ bsum, int nb) {  // single block, 128 thr
  __shared__ int sm[128];
  int v = (threadIdx.x < nb) ? bsum[threadIdx.x] : 0;
  sm[threadIdx.x] = v;
  __syncthreads();
  for (int st = 1; st < 128; st <<= 1) {
    int t = (threadIdx.x >= st) ? sm[threadIdx.x - st] : 0;
    __syncthreads();
    sm[threadIdx.x] += t;
    __syncthreads();
  }
  if (threadIdx.x < nb) bsum[threadIdx.x] = sm[threadIdx.x] - v;  // exclusive
}

__global__ void k_scan_final(const int* __restrict__ deg, const int* __restrict__ bsum,
                             int* __restrict__ rowptr) {
  __shared__ int sm[1024];
  int i = blockIdx.x * 1024 + threadIdx.x;
  int v = (i < N_NODES) ? deg[i] : 0;
  sm[threadIdx.x] = v;
  __syncthreads();
  for (int st = 1; st < 1024; st <<= 1) {
    int t = (threadIdx.x >= st) ? sm[threadIdx.x - st] : 0;
    __syncthreads();
    sm[threadIdx.x] += t;
    __syncthreads();
  }
  int excl = sm[threadIdx.x] - v + bsum[blockIdx.x];
  if (i < N_NODES) rowptr[i] = excl;
}

// bucket write-cursors from rowptr (bucket b covers nodes [b*391, ...))
__global__ void k_bcur(const int* __restrict__ rowptr, unsigned* __restrict__ gbcur) {
  int b = threadIdx.x;
  if (b < BUCKETS) gbcur[b] = (unsigned)rowptr[b * BUCKET_NODES];
}

// pass 1: LDS-binned burst scatter of 8B records (row|col|qlew) into bucket regions
__global__ void k_fill_p1(const int* __restrict__ ei, const float* __restrict__ ew,
                          unsigned* __restrict__ gbcur,
                          unsigned long long* __restrict__ tmp) {
  __shared__ unsigned cnt[BUCKETS], gbase[BUCKETS], lofs[BUCKETS];
  int t = threadIdx.x;
  cnt[t] = 0;
  __syncthreads();
  int base = blockIdx.x * P1_EDGES;
#pragma unroll
  for (int i = 0; i < 16; ++i) {
    int e = base + i * 256 + t;
    if (e < N_EDGES) atomicAdd(&cnt[(unsigned)ei[e] / BUCKET_NODES], 1u);
  }
  __syncthreads();
  {
    unsigned c = cnt[t];
    gbase[t] = c ? atomicAdd(&gbcur[t], c) : 0u;
    lofs[t] = 0;
  }
  __syncthreads();
#pragma unroll
  for (int i = 0; i < 16; ++i) {
    int e = base + i * 256 + t;
    if (e < N_EDGES) {
      unsigned r = (unsigned)ei[e], c = (unsigned)ei[N_EDGES + e];
      float lew = __logf(ew[e]);
      lew = fmaxf(lew, -15.9995f);
      unsigned q = (unsigned)(-lew * LEW_SCALE + 0.5f);
      if (q > 32767u) q = 32767u;
      unsigned b = r / BUCKET_NODES;
      unsigned idx = atomicAdd(&lofs[b], 1u);
      tmp[gbase[b] + idx] = ((unsigned long long)r << 32)
                          | ((unsigned long long)c << 15) | q;
    }
  }
}

// pass 2: per-bucket exact placement; scattered 4B writes stay in one ~20KB L2 window
__global__ void k_fill_p2(const int* __restrict__ rowptr,
                          const unsigned long long* __restrict__ tmp,
                          unsigned* __restrict__ packed) {
  __shared__ int lcur[BUCKET_NODES];
  int b = blockIdx.x, t = threadIdx.x;
  int nb0 = b * BUCKET_NODES;
  int nb1 = min(nb0 + BUCKET_NODES, N_NODES);
  int nn = nb1 - nb0;
  for (int j = t; j < nn; j += 256) lcur[j] = rowptr[nb0 + j];
  __syncthreads();
  int beg = rowptr[nb0];
  int end = (nb1 < N_NODES) ? rowptr[nb1] : N_EDGES;
  for (int i = beg + t; i < end; i += 256) {
    unsigned long long rec = tmp[i];
    int r = (int)(rec >> 32);
    int pos = atomicAdd(&lcur[r - nb0], 1);
    packed[pos] = (unsigned)(rec & 0xFFFFFFFFu);
  }
}

// rows_sorted: sequential fill from rowptr/deg (no scatter)
__global__ void k_rows(const int* __restrict__ rowptr, const int* __restrict__ deg,
                       int* __restrict__ rows_sorted) {
  int n = blockIdx.x * 256 + threadIdx.x;
  if (n >= N_NODES) return;
  int beg = rowptr[n], d = deg[n];
  for (int i = 0; i < d; ++i) rows_sorted[beg + i] = n;
}

// ---------------- per-layer u = W @ a  (alpha decomposition) ----------------
__global__ void k_prep(const float* __restrict__ lin_W,  // [3][64][64]
                       const float* __restrict__ lin_b,  // [3][64]
                       const float* __restrict__ att_W,  // [3][128]
                       float* __restrict__ uvec,         // [3][2][64]
                       float* __restrict__ ucst) {       // [3][2]
  int l = blockIdx.x, j = threadIdx.x;
  const float* Wl = lin_W + l * HID * HID;
  const float* a1 = att_W + l * 2 * HID;
  const float* a2 = a1 + HID;
  float s1 = 0.f, s2 = 0.f;
  for (int c = 0; c < HID; ++c) {
    float w = Wl[j * HID + c];
    s1 += w * a1[c];
    s2 += w * a2[c];
  }
  uvec[l * 128 + j] = s1;
  uvec[l * 128 + 64 + j] = s2;
  float t1 = lin_b[l * HID + j] * a1[j];
  float t2 = lin_b[l * HID + j] * a2[j];
#pragma unroll
  for (int off = 32; off > 0; off >>= 1) {
    t1 += __shfl_xor(t1, off, 64);
    t2 += __shfl_xor(t2, off, 64);
  }
  if (j == 0) { ucst[l * 2] = t1; ucst[l * 2 + 1] = t2; }
}

// ---------------- MFMA linear: hl = h@W + b (fp32 + bf16 mirror); alphas ----------------
__global__ void k_lin_mfma(const float* __restrict__ h,
                           const float* __restrict__ W,     // [64][64] this layer
                           const float* __restrict__ bias,  // [64]
                           const float* __restrict__ uvec,  // [2][64] this layer
                           const float* __restrict__ ucst,  // [2]
                           float* __restrict__ hl,
                           unsigned short* __restrict__ hl2, // bf16 mirror
                           float* __restrict__ alpha1,
                           float* __restrict__ alpha2) {
  __shared__ unsigned short Wt[HID * 72];  // Wt[n][k] bf16, row stride 72
  for (int idx = threadIdx.x; idx < HID * HID; idx += 256) {
    int k = idx >> 6, n = idx & 63;
    Wt[n * 72 + k] = f2bf(W[idx]);
  }
  __syncthreads();

  int wave = threadIdx.x >> 6, lane = threadIdx.x & 63;
  int g = lane >> 4, r = lane & 15;
  int nb = blockIdx.x * 64 + wave * 16;
  int row = nb + r;
  bool rowok = row < N_NODES;

  f32x4 f0 = {0,0,0,0}, f1 = {0,0,0,0}, f2v = {0,0,0,0}, f3 = {0,0,0,0};
  if (rowok) {
    const float* hrow = h + (size_t)row * HID;
    f0  = *(const f32x4*)(hrow + g * 8);
    f1  = *(const f32x4*)(hrow + g * 8 + 4);
    f2v = *(const f32x4*)(hrow + 32 + g * 8);
    f3  = *(const f32x4*)(hrow + 32 + g * 8 + 4);
  }
  bf16x8 a0, a1f;
#pragma unroll
  for (int i = 0; i < 4; ++i) {
    a0[i]      = (short)f2bf(f0[i]);
    a0[i + 4]  = (short)f2bf(f1[i]);
    a1f[i]     = (short)f2bf(f2v[i]);
    a1f[i + 4] = (short)f2bf(f3[i]);
  }

  f32x4 acc[4] = {{0,0,0,0},{0,0,0,0},{0,0,0,0},{0,0,0,0}};
#pragma unroll
  for (int nt = 0; nt < 4; ++nt) {
    bf16x8 b0 = *(const bf16x8*)&Wt[(nt * 16 + r) * 72 + g * 8];
    bf16x8 b1 = *(const bf16x8*)&Wt[(nt * 16 + r) * 72 + 32 + g * 8];
    acc[nt] = __builtin_amdgcn_mfma_f32_16x16x32_bf16(a0, b0, acc[nt], 0, 0, 0);
    acc[nt] = __builtin_amdgcn_mfma_f32_16x16x32_bf16(a1f, b1, acc[nt], 0, 0, 0);
  }

  // alphas from fp32 h fragments
  {
    const float* u1 = uvec;
    const float* u2 = uvec + HID;
    f32x4 ua = *(const f32x4*)(u1 + g * 8),      ub = *(const f32x4*)(u1 + g * 8 + 4);
    f32x4 uc = *(const f32x4*)(u1 + 32 + g * 8), ud = *(const f32x4*)(u1 + 32 + g * 8 + 4);
    float p1 = f0[0]*ua[0]+f0[1]*ua[1]+f0[2]*ua[2]+f0[3]*ua[3]
             + f1[0]*ub[0]+f1[1]*ub[1]+f1[2]*ub[2]+f1[3]*ub[3]
             + f2v[0]*uc[0]+f2v[1]*uc[1]+f2v[2]*uc[2]+f2v[3]*uc[3]
             + f3[0]*ud[0]+f3[1]*ud[1]+f3[2]*ud[2]+f3[3]*ud[3];
    ua = *(const f32x4*)(u2 + g * 8);      ub = *(const f32x4*)(u2 + g * 8 + 4);
    uc = *(const f32x4*)(u2 + 32 + g * 8); ud = *(const f32x4*)(u2 + 32 + g * 8 + 4);
    float p2 = f0[0]*ua[0]+f0[1]*ua[1]+f0[2]*ua[2]+f0[3]*ua[3]
             + f1[0]*ub[0]+f1[1]*ub[1]+f1[2]*ub[2]+f1[3]*ub[3]
             + f2v[0]*uc[0]+f2v[1]*uc[1]+f2v[2]*uc[2]+f2v[3]*uc[3]
             + f3[0]*ud[0]+f3[1]*ud[1]+f3[2]*ud[2]+f3[3]*ud[3];
    p1 += __shfl_xor(p1, 16, 64); p1 += __shfl_xor(p1, 32, 64);
    p2 += __shfl_xor(p2, 16, 64); p2 += __shfl_xor(p2, 32, 64);
    if (g == 0 && rowok) {
      alpha1[row] = p1 + ucst[0];
      alpha2[row] = p2 + ucst[1];
    }
  }

  // store hl (+bias) fp32 + bf16 mirror. D: col = nt*16 + r, node = nb + g*4 + reg
#pragma unroll
  for (int nt = 0; nt < 4; ++nt) {
    float bv = bias[nt * 16 + r];
#pragma unroll
    for (int reg = 0; reg < 4; ++reg) {
      int n2 = nb + g * 4 + reg;
      if (n2 < N_NODES) {
        float v = acc[nt][reg] + bv;
        hl[(size_t)n2 * HID + nt * 16 + r] = v;
        hl2[(size_t)n2 * HID + nt * 16 + r] = f2bf(v);
      }
    }
  }
}

// ---------------- per-layer edge pass (CSR order) + fused ticket combine ----------------
// writes sl[p] = leaky(score) + log(ew); reduces max/sum of leaky(score)
__global__ void k_edge(const int* __restrict__ rows_sorted,
                       const unsigned* __restrict__ packed,
                       const float* __restrict__ alpha1,
                       const float* __restrict__ alpha2,
                       const float* __restrict__ attB,
                       float* __restrict__ slw,
                       float* __restrict__ pmax,
                       float* __restrict__ psum,
                       int* __restrict__ counter,
                       float* __restrict__ red) {
  int t = threadIdx.x;
  int base = blockIdx.x * EDGE_CHUNK;
  float ab = attB[0];
  float m = -INFINITY, sum = 0.f;
#pragma unroll
  for (int i = 0; i < 8; ++i) {
    int p = base + i * 256 + t;
    if (p < N_EDGES) {
      unsigned u = packed[p];
      int r = rows_sorted[p];
      float sc = alpha1[r] + alpha2[u >> 15] + ab;
      sc = sc > 0.f ? sc : SLOPE * sc;
      slw[p] = sc - (float)(u & 0x7FFFu) * LEW_INV;
      if (sc > m) { sum *= __expf(m - sc); m = sc; }
      sum += __expf(sc - m);
    }
  }
  __shared__ float smax[256], ssum[256];
  __shared__ bool last;
  smax[t] = m; ssum[t] = sum;
  __syncthreads();
  for (int st = 128; st > 0; st >>= 1) {
    if (t < st) {
      float ma = smax[t], mb = smax[t + st];
      float sa = ssum[t], sb = ssum[t + st];
      float mm = fmaxf(ma, mb);
      float ss = 0.f;
      if (mm != -INFINITY)
        ss = (ma == -INFINITY ? 0.f : sa * __expf(ma - mm))
           + (mb == -INFINITY ? 0.f : sb * __expf(mb - mm));
      smax[t] = mm; ssum[t] = ss;
    }
    __syncthreads();
  }
  if (t == 0) {
    pmax[blockIdx.x] = smax[0];
    psum[blockIdx.x] = ssum[0];
    __threadfence();
    int old = atomicAdd(counter, 1);
    last = (old == (int)gridDim.x - 1);
  }
  __syncthreads();
  if (!last) return;
  __threadfence();
  volatile const float* vpm = pmax;
  volatile const float* vps = psum;
  float m2 = -INFINITY, s2 = 0.f;
  for (int i = t; i < (int)gridDim.x; i += 256) {
    float mb = vpm[i], sb = vps[i];
    if (mb != -INFINITY) {
      if (mb > m2) { s2 *= __expf(m2 - mb); m2 = mb; }
      s2 += sb * __expf(mb - m2);
    }
  }
  __syncthreads();
  smax[t] = m2; ssum[t] = s2;
  __syncthreads();
  for (int st = 128; st > 0; st >>= 1) {
    if (t < st) {
      float ma = smax[t], mb = smax[t + st];
      float sa = ssum[t], sb = ssum[t + st];
      float mm = fmaxf(ma, mb);
      float ss = 0.f;
      if (mm != -INFINITY)
        ss = (ma == -INFINITY ? 0.f : sa * __expf(ma - mm))
           + (mb == -INFINITY ? 0.f : sb * __expf(mb - mm));
      smax[t] = mm; ssum[t] = ss;
    }
    __syncthreads();
  }
  if (t == 0) {
    red[0] = smax[0];
    red[1] = ssum[0];
    *counter = 0;   // self-reset for next layer / replay
  }
}

// sl -> w = exp(sl - M), in place (edge-parallel: 1 exp per edge)
__global__ void k_exp2(float* __restrict__ slw, const float* __restrict__ red) {
  int e = blockIdx.x * 256 + threadIdx.x;
  if (e < N_EDGES) slw[e] = __expf(slw[e] - red[0]);
}

// ---------------- fused CSR aggregate (bf16 gather, streamed coef) + relu + LN + residual ----
__global__ void k_agg_update(const int* __restrict__ rowptr,
                             const int* __restrict__ deg,
                             const unsigned* __restrict__ packed,
                             const float* __restrict__ w,
                             const float* __restrict__ red,  // [1]=S
                             const float* __restrict__ hl,
                             const unsigned short* __restrict__ hl2,
                             const float* __restrict__ g,
                             const float* __restrict__ b,
                             float* __restrict__ h) {
  int wave = threadIdx.x >> 6, lane = threadIdx.x & 63;
  int n = blockIdx.x * 4 + wave;
  if (n >= N_NODES) return;
  int beg = rowptr[n];
  int end = beg + deg[n];
  float acc = 0.f;
  int k = beg;
  for (; k + 3 < end; k += 4) {
    unsigned u0 = packed[k],     u1 = packed[k + 1];
    unsigned u2 = packed[k + 2], u3 = packed[k + 3];
    float w0 = w[k], w1 = w[k + 1], w2 = w[k + 2], w3 = w[k + 3];
    float v0 = bf2f(hl2[(size_t)(u0 >> 15) * HID + lane]);
    float v1 = bf2f(hl2[(size_t)(u1 >> 15) * HID + lane]);
    float v2 = bf2f(hl2[(size_t)(u2 >> 15) * HID + lane]);
    float v3 = bf2f(hl2[(size_t)(u3 >> 15) * HID + lane]);
    acc += w0 * v0 + w1 * v1 + w2 * v2 + w3 * v3;
  }
  for (; k < end; ++k)
    acc += w[k] * bf2f(hl2[(size_t)(packed[k] >> 15) * HID + lane]);

  float inv = 1.0f / red[1];
  float v = hl[(size_t)n * HID + lane] + acc * inv;
  v = fmaxf(v, 0.f);
  float m = v;
#pragma unroll
  for (int off = 32; off > 0; off >>= 1) m += __shfl_xor(m, off, 64);
  m *= (1.0f / HID);
  float d = v - m;
  float var = d * d;
#pragma unroll
  for (int off = 32; off > 0; off >>= 1) var += __shfl_xor(var, off, 64);
  var *= (1.0f / HID);
  float nv = d * rsqrtf(var + LN_EPS);
  h[(size_t)n * HID + lane] += nv * g[lane] + b[lane];
}

// ---------------- output head via MFMA ----------------
__global__ void k_out_mfma(const float* __restrict__ h,
                           const float* __restrict__ W1,  // [64][32]
                           const float* __restrict__ b1,  // [32]
                           const float* __restrict__ W2,  // [32]
                           const float* __restrict__ b2,  // [1]
                           float* __restrict__ out) {
  __shared__ unsigned short W1t[32 * 72];  // W1t[m][k] bf16
  __shared__ float sW2[32];
  for (int idx = threadIdx.x; idx < HID * 32; idx += 256) {
    int k = idx >> 5, m = idx & 31;
    W1t[m * 72 + k] = f2bf(W1[idx]);
  }
  if (threadIdx.x < 32) sW2[threadIdx.x] = W2[threadIdx.x];
  __syncthreads();

  int wave = threadIdx.x >> 6, lane = threadIdx.x & 63;
  int g = lane >> 4, r = lane & 15;
  int nb = blockIdx.x * 64 + wave * 16;
  int row = nb + r;
  bool rowok = row < N_NODES;

  f32x4 f0 = {0,0,0,0}, f1 = {0,0,0,0}, f2v = {0,0,0,0}, f3 = {0,0,0,0};
  if (rowok) {
    const float* hrow = h + (size_t)row * HID;
    f0  = *(const f32x4*)(hrow + g * 8);
    f1  = *(const f32x4*)(hrow + g * 8 + 4);
    f2v = *(const f32x4*)(hrow + 32 + g * 8);
    f3  = *(const f32x4*)(hrow + 32 + g * 8 + 4);
  }
  bf16x8 a0, a1f;
#pragma unroll
  for (int i = 0; i < 4; ++i) {
    a0[i]      = (short)f2bf(f0[i]);
    a0[i + 4]  = (short)f2bf(f1[i]);
    a1f[i]     = (short)f2bf(f2v[i]);
    a1f[i + 4] = (short)f2bf(f3[i]);
  }

  f32x4 acc[2] = {{0,0,0,0},{0,0,0,0}};
#pragma unroll
  for (int mt = 0; mt < 2; ++mt) {
    bf16x8 b0 = *(const bf16x8*)&W1t[(mt * 16 + r) * 72 + g * 8];
    bf16x8 b1v = *(const bf16x8*)&W1t[(mt * 16 + r) * 72 + 32 + g * 8];
    acc[mt] = __builtin_amdgcn_mfma_f32_16x16x32_bf16(a0, b0, acc[mt], 0, 0, 0);
    acc[mt] = __builtin_amdgcn_mfma_f32_16x16x32_bf16(a1f, b1v, acc[mt], 0, 0, 0);
  }

  float part[4];
#pragma unroll
  for (int reg = 0; reg < 4; ++reg) {
    float p = 0.f;
#pragma unroll
    for (int mt = 0; mt < 2; ++mt) {
      float z = acc[mt][reg] + b1[mt * 16 + r];
      p += fmaxf(z, 0.f) * sW2[mt * 16 + r];
    }
    p += __shfl_xor(p, 1, 64);
    p += __shfl_xor(p, 2, 64);
    p += __shfl_xor(p, 4, 64);
    p += __shfl_xor(p, 8, 64);
    part[reg] = p;
  }
  if (r == 0) {
    float bb = b2[0];
#pragma unroll
    for (int reg = 0; reg < 4; ++reg) {
      int n2 = nb + g * 4 + reg;
      if (n2 < N_NODES)
        out[n2] = 1.0f / (1.0f + expf(-(part[reg] + bb)));
    }
  }
}

extern "C" void kernel_launch(void* const* d_in, const int* in_sizes, int n_in,
                              void* d_out, int out_size, void* d_ws, size_t ws_size,
                              hipStream_t stream) {
  const float* x      = (const float*)d_in[0];
  const int*   ei     = (const int*)d_in[1];     // [2][E]
  const float* ew     = (const float*)d_in[2];
  const float* in_W   = (const float*)d_in[3];
  const float* in_b   = (const float*)d_in[4];
  const float* lin_W  = (const float*)d_in[5];   // [3][64][64]
  const float* lin_b  = (const float*)d_in[6];   // [3][64]
  const float* att_W  = (const float*)d_in[7];   // [3][128]
  const float* att_b  = (const float*)d_in[8];   // [3]
  const float* ln_g   = (const float*)d_in[9];   // [3][64]
  const float* ln_b   = (const float*)d_in[10];  // [3][64]
  const float* out1_W = (const float*)d_in[11];  // [64][32]
  const float* out1_b = (const float*)d_in[12];  // [32]
  const float* out2_W = (const float*)d_in[13];  // [32]
  const float* out2_b = (const float*)d_in[14];  // [1]
  float* out = (float*)d_out;

  float* ws = (float*)d_ws;
  float* h            = ws;                         // 6.4M f
  float* hl           = ws + 6400000;               // 6.4M f
  unsigned short* hl2 = (unsigned short*)(ws + 12800000);      // 6.4M bf16
  unsigned long long* tmp = (unsigned long long*)(ws + 16000000);  // 1.25M u64
  unsigned* packed    = (unsigned*)(ws + 18500000); // 1.25M u32
  float* slw          = ws + 19750000;              // 1.25M f (scores -> coefs)
  int* rows_sorted    = (int*)(ws + 21000000);      // 1.25M i
  int* deg            = (int*)(ws + 22250000);      // 100000 (+1 ticket counter)
  int* counter        = deg + N_NODES;
  int* rowptr         = (int*)(ws + 22360000);
  float* alpha1       = ws + 22470000;
  float* alpha2       = ws + 22580000;
  float* pmax         = ws + 22690000;              // 1024
  float* psum         = ws + 22692000;              // 1024
  float* red          = ws + 22694000;              // [0]=M, [1]=S
  float* uvec         = ws + 22695000;              // [3][2][64]
  float* ucst         = ws + 22696000;              // [3][2]
  int* bsum           = (int*)(ws + 22697000);      // 128
  unsigned* gbcur     = (unsigned*)(ws + 22698000); // 256

  // ---- one-time CSR build ----
  hipMemsetAsync(deg, 0, (N_NODES + 1) * sizeof(int), stream);  // deg + ticket counter
  k_hist<<<EDGE_TBLOCKS, 256, 0, stream>>>(ei, deg);
  k_blocksums<<<SCAN_BLOCKS, 1024, 0, stream>>>(deg, bsum);
  k_scan_bsums<<<1, 128, 0, stream>>>(bsum, SCAN_BLOCKS);
  k_scan_final<<<SCAN_BLOCKS, 1024, 0, stream>>>(deg, bsum, rowptr);
  k_bcur<<<1, 256, 0, stream>>>(rowptr, gbcur);
  k_fill_p1<<<P1_BLOCKS, 256, 0, stream>>>(ei, ew, gbcur, tmp);
  k_fill_p2<<<BUCKETS, 256, 0, stream>>>(rowptr, tmp, packed);
  k_rows<<<(N_NODES + 255) / 256, 256, 0, stream>>>(rowptr, deg, rows_sorted);

  k_prep<<<N_LAYERS, 64, 0, stream>>>(lin_W, lin_b, att_W, uvec, ucst);
  k_in_proj<<<NODE_BLOCKS, 256, 0, stream>>>(x, in_W, in_b, h);

  for (int i = 0; i < N_LAYERS; ++i) {
    k_lin_mfma<<<MFMA_BLOCKS, 256, 0, stream>>>(h, lin_W + i * HID * HID, lin_b + i * HID,
                                                uvec + i * 128, ucst + i * 2,
                                                hl, hl2, alpha1, alpha2);
    k_edge<<<EDGE_BLOCKS, 256, 0, stream>>>(rows_sorted, packed, alpha1, alpha2,
                                            att_b + i, slw, pmax, psum, counter, red);
    k_exp2<<<EDGE_TBLOCKS, 256, 0, stream>>>(slw, red);
    k_agg_update<<<NODE_BLOCKS, 256, 0, stream>>>(rowptr, deg, packed, slw, red,
                                                  hl, hl2, ln_g + i * HID, ln_b + i * HID, h);
  }

  k_out_mfma<<<MFMA_BLOCKS, 256, 0, stream>>>(h, out1_W, out1_b, out2_W, out2_b, out);
}